// Round 1
// baseline (6984.880 us; speedup 1.0000x reference)
//
#include <hip/hip_runtime.h>
#include <math.h>

#define E_ 4
#define B_ 16
#define S_ 224
#define P_ 16
#define D_ 384
#define H_ 6
#define HD_ 64
#define L_ 12
#define FF_ 1536
#define NC_ 10
#define NP_ 196
#define T_ 197
#define GATE_K (3 * S_ * S_)  // 150528

// ---------------- gate: logits = x_flat @ gate_w + gate_b ; idx = argmax ----------------
__global__ void gate_kernel(const float* __restrict__ x, const float* __restrict__ gw,
                            const float* __restrict__ gb, int* __restrict__ idx) {
  int b = blockIdx.x;
  int tid = threadIdx.x;
  const float* xb = x + (size_t)b * GATE_K;
  const float4* gw4 = (const float4*)gw;  // rows of 4 floats, 16B aligned
  float4 acc = make_float4(0.f, 0.f, 0.f, 0.f);
  for (int i = tid; i < GATE_K; i += 256) {
    float xv = xb[i];
    float4 w = gw4[i];
    acc.x += xv * w.x; acc.y += xv * w.y; acc.z += xv * w.z; acc.w += xv * w.w;
  }
  __shared__ float4 red[256];
  red[tid] = acc;
  __syncthreads();
  for (int off = 128; off > 0; off >>= 1) {
    if (tid < off) {
      float4 o = red[tid + off];
      red[tid].x += o.x; red[tid].y += o.y; red[tid].z += o.z; red[tid].w += o.w;
    }
    __syncthreads();
  }
  if (tid == 0) {
    float v[4] = {red[0].x + gb[0], red[0].y + gb[1], red[0].z + gb[2], red[0].w + gb[3]};
    int best = 0;
    for (int e = 1; e < 4; ++e) if (v[e] > v[best]) best = e;  // first-max like jnp.argmax
    idx[b] = best;
  }
}

// ---------------- cls row: t[b][0] = cls[e] + pos[e][0] ----------------
__global__ void cls_kernel(const float* __restrict__ cls, const float* __restrict__ pos,
                           const int* __restrict__ idx, float* __restrict__ t) {
  int b = blockIdx.x;
  int d = threadIdx.x;
  int e = idx[b];
  t[((size_t)b * T_) * D_ + d] = cls[e * D_ + d] + pos[((size_t)e * T_) * D_ + d];
}

// ---------------- patch embed: t[b][1+m] = xp[b,m] @ patch_w[e] + patch_b[e] + pos[e][1+m] ----------------
// 14 patch rows per block, xp rows staged in LDS, weight row reused x14.
__global__ void patch_kernel(const float* __restrict__ x, const float* __restrict__ pw,
                             const float* __restrict__ pb, const float* __restrict__ pos,
                             const int* __restrict__ idx, float* __restrict__ t) {
  int b = blockIdx.y;
  int e = idx[b];
  int m0 = blockIdx.x * 14;
  int tid = threadIdx.x;  // 384 threads
  __shared__ float xin[14][768];
  for (int jj = tid; jj < 14 * 768; jj += 384) {
    int r = jj / 768, j = jj - r * 768;
    int m = m0 + r;
    int pr = m / 14, pc = m - pr * 14;
    int c = j >> 8, y = (j >> 4) & 15, xx = j & 15;
    xin[r][j] = x[(((size_t)b * 3 + c) * S_ + (pr * 16 + y)) * S_ + pc * 16 + xx];
  }
  __syncthreads();
  int d = tid;  // one output column per thread
  float acc[14];
#pragma unroll
  for (int r = 0; r < 14; ++r) acc[r] = 0.f;
  const float* pwe = pw + (size_t)e * 768 * D_;
  for (int k = 0; k < 768; ++k) {
    float wv = pwe[(size_t)k * D_ + d];
#pragma unroll
    for (int r = 0; r < 14; ++r) acc[r] += xin[r][k] * wv;
  }
  float bias = pb[e * D_ + d];
#pragma unroll
  for (int r = 0; r < 14; ++r) {
    int row = 1 + m0 + r;
    t[((size_t)b * T_ + row) * D_ + d] = acc[r] + bias + pos[((size_t)e * T_ + row) * D_ + d];
  }
}

// ---------------- layernorm: out = (in-mean)*rsqrt(var+eps)*w + b (per row of D=384) ----------------
// 4 rows per block, one wave (64 lanes) per row, 6 elements per lane.
__global__ void ln_kernel(const float* __restrict__ in, float* __restrict__ out,
                          const float* __restrict__ w, const float* __restrict__ bc,
                          const int* __restrict__ idx, int l) {
  int b = blockIdx.y;
  int row = blockIdx.x * 4 + (threadIdx.x >> 6);
  if (row >= T_) return;
  int lane = threadIdx.x & 63;
  int e = idx[b];
  const float* rp = in + ((size_t)b * T_ + row) * D_;
  float v[6];
  float s = 0.f;
#pragma unroll
  for (int j = 0; j < 6; ++j) { v[j] = rp[lane + j * 64]; s += v[j]; }
#pragma unroll
  for (int off = 1; off < 64; off <<= 1) s += __shfl_xor(s, off);
  float mean = s * (1.f / 384.f);
  float sq = 0.f;
#pragma unroll
  for (int j = 0; j < 6; ++j) { float dd = v[j] - mean; sq += dd * dd; }
#pragma unroll
  for (int off = 1; off < 64; off <<= 1) sq += __shfl_xor(sq, off);
  float rs = rsqrtf(sq * (1.f / 384.f) + 1e-6f);
  const float* wrow = w + ((size_t)e * L_ + l) * D_;
  const float* brow = bc + ((size_t)e * L_ + l) * D_;
  float* op = out + ((size_t)b * T_ + row) * D_;
#pragma unroll
  for (int j = 0; j < 6; ++j) {
    int d = lane + j * 64;
    op[d] = (v[j] - mean) * rs * wrow[d] + brow[d];
  }
}

// ---------------- tiled fp32 GEMM: Out[b] = A[b] @ W[e,l] + bias[e,l] (+epilogue) ----------------
// EPI: 0 = store, 1 = residual add (Out += ...), 2 = exact GELU then store.
// BM=BN=64, BK=16, 256 threads, 4x4 micro-tile.
template <int EPI>
__global__ void gemm_kernel(const float* __restrict__ A, const float* __restrict__ W,
                            const float* __restrict__ bias, float* __restrict__ Out,
                            const int* __restrict__ idx, int l, int K, int N) {
  int b = blockIdx.z;
  int e = idx[b];
  int n0 = blockIdx.x * 64;
  int m0 = blockIdx.y * 64;
  int tid = threadIdx.x;
  const float* Ab = A + (size_t)b * T_ * K;
  const float* Wb = W + ((size_t)e * L_ + l) * (size_t)K * N;
  __shared__ float As[16][64];  // [k][m]
  __shared__ float Bs[16][64];  // [k][n]
  float acc[4][4] = {};
  int tx = tid & 15, ty = tid >> 4;
  int am = tid >> 2, akq = (tid & 3) * 4;   // A load: row am, k-quad akq
  int bk = tid >> 4, bnq = (tid & 15) * 4;  // B load: k-row bk, n-quad bnq
  for (int k0 = 0; k0 < K; k0 += 16) {
    int row = m0 + am;
    float4 av = make_float4(0.f, 0.f, 0.f, 0.f);
    if (row < T_) av = *(const float4*)(Ab + (size_t)row * K + k0 + akq);
    As[akq + 0][am] = av.x;
    As[akq + 1][am] = av.y;
    As[akq + 2][am] = av.z;
    As[akq + 3][am] = av.w;
    float4 bv = *(const float4*)(Wb + (size_t)(k0 + bk) * N + n0 + bnq);
    *(float4*)&Bs[bk][bnq] = bv;
    __syncthreads();
#pragma unroll
    for (int k = 0; k < 16; ++k) {
      float4 a4 = *(const float4*)&As[k][ty * 4];
      float4 b4 = *(const float4*)&Bs[k][tx * 4];
      float ar[4] = {a4.x, a4.y, a4.z, a4.w};
      float br[4] = {b4.x, b4.y, b4.z, b4.w};
#pragma unroll
      for (int r = 0; r < 4; ++r)
#pragma unroll
        for (int c = 0; c < 4; ++c) acc[r][c] += ar[r] * br[c];
    }
    __syncthreads();
  }
  const float* brow = bias + ((size_t)e * L_ + l) * N + n0;
#pragma unroll
  for (int r = 0; r < 4; ++r) {
    int row = m0 + ty * 4 + r;
    if (row >= T_) continue;
    float* orow = Out + ((size_t)b * T_ + row) * N + n0;
#pragma unroll
    for (int c = 0; c < 4; ++c) {
      int col = tx * 4 + c;
      float val = acc[r][c] + brow[col];
      if (EPI == 1) val += orow[col];
      if (EPI == 2) val = 0.5f * val * (1.f + erff(val * 0.70710678118654752f));
      orow[col] = val;
    }
  }
}

// ---------------- attention: per (b, head, 16-row q-tile); scores in LDS, 2-pass softmax ----------------
__global__ void attn_kernel(const float* __restrict__ qkv, float* __restrict__ o) {
  int b = blockIdx.z, h = blockIdx.y, qt = blockIdx.x;
  int q0 = qt * 16;
  int tid = threadIdx.x;  // 256
  __shared__ float Qs[16][64];
  __shared__ float Sc[16][200];
  {
    int qi = tid >> 4, dq = (tid & 15) * 4;
    int row = q0 + qi;
    float4 qv = make_float4(0.f, 0.f, 0.f, 0.f);
    if (row < T_) qv = *(const float4*)(qkv + ((size_t)b * T_ + row) * (3 * D_) + h * HD_ + dq);
    *(float4*)&Qs[qi][dq] = qv;
  }
  __syncthreads();
  {
    int kk = tid & 63, qq = tid >> 6;
    for (int kb = 0; kb < T_; kb += 64) {
      int k = kb + kk;
      if (k < T_) {
        const float4* Kr = (const float4*)(qkv + ((size_t)b * T_ + k) * (3 * D_) + D_ + h * HD_);
#pragma unroll
        for (int j = 0; j < 4; ++j) {
          int qi = qq * 4 + j;
          float accs = 0.f;
#pragma unroll
          for (int dc = 0; dc < 16; ++dc) {
            float4 kv = Kr[dc];
            accs += kv.x * Qs[qi][dc * 4 + 0] + kv.y * Qs[qi][dc * 4 + 1] +
                    kv.z * Qs[qi][dc * 4 + 2] + kv.w * Qs[qi][dc * 4 + 3];
          }
          Sc[qi][k] = accs * 0.125f;  // 1/sqrt(64)
        }
      }
    }
  }
  __syncthreads();
  {
    int r = tid >> 4, l16 = tid & 15;
    float mx = -1e30f;
    for (int k = l16; k < T_; k += 16) mx = fmaxf(mx, Sc[r][k]);
#pragma unroll
    for (int off = 8; off > 0; off >>= 1) mx = fmaxf(mx, __shfl_xor(mx, off, 16));
    float sum = 0.f;
    for (int k = l16; k < T_; k += 16) {
      float p = expf(Sc[r][k] - mx);
      Sc[r][k] = p;
      sum += p;
    }
#pragma unroll
    for (int off = 8; off > 0; off >>= 1) sum += __shfl_xor(sum, off, 16);
    float inv = 1.f / sum;
    for (int k = l16; k < T_; k += 16) Sc[r][k] *= inv;
  }
  __syncthreads();
  {
    int dd = tid & 63, qq = tid >> 6;
    float acc[4] = {0.f, 0.f, 0.f, 0.f};
    for (int k = 0; k < T_; ++k) {
      float v = qkv[((size_t)b * T_ + k) * (3 * D_) + 2 * D_ + h * HD_ + dd];
#pragma unroll
      for (int j = 0; j < 4; ++j) acc[j] += Sc[qq * 4 + j][k] * v;
    }
#pragma unroll
    for (int j = 0; j < 4; ++j) {
      int row = q0 + qq * 4 + j;
      if (row < T_) o[((size_t)b * T_ + row) * D_ + h * HD_ + dd] = acc[j];
    }
  }
}

// ---------------- final LN(row 0) + head ----------------
__global__ void head_kernel(const float* __restrict__ t, const float* __restrict__ nw,
                            const float* __restrict__ nb, const float* __restrict__ hw,
                            const float* __restrict__ hb, const int* __restrict__ idx,
                            float* __restrict__ out) {
  int b = blockIdx.x;
  int e = idx[b];
  int lane = threadIdx.x;  // 64
  const float* rp = t + (size_t)b * T_ * D_;
  float v[6];
  float s = 0.f;
#pragma unroll
  for (int j = 0; j < 6; ++j) { v[j] = rp[lane + j * 64]; s += v[j]; }
#pragma unroll
  for (int off = 1; off < 64; off <<= 1) s += __shfl_xor(s, off);
  float mean = s * (1.f / 384.f);
  float sq = 0.f;
#pragma unroll
  for (int j = 0; j < 6; ++j) { float dd = v[j] - mean; sq += dd * dd; }
#pragma unroll
  for (int off = 1; off < 64; off <<= 1) sq += __shfl_xor(sq, off);
  float rs = rsqrtf(sq * (1.f / 384.f) + 1e-6f);
  __shared__ float ln[D_];
#pragma unroll
  for (int j = 0; j < 6; ++j) {
    int d = lane + j * 64;
    ln[d] = (v[j] - mean) * rs * nw[e * D_ + d] + nb[e * D_ + d];
  }
  __syncthreads();
  if (lane < NC_) {
    float acc = hb[e * NC_ + lane];
    for (int d = 0; d < D_; ++d) acc += ln[d] * hw[((size_t)e * D_ + d) * NC_ + lane];
    out[b * NC_ + lane] = acc;
  }
}

extern "C" void kernel_launch(void* const* d_in, const int* in_sizes, int n_in,
                              void* d_out, int out_size, void* d_ws, size_t ws_size,
                              hipStream_t stream) {
  const float* x      = (const float*)d_in[0];
  const float* gate_w = (const float*)d_in[1];
  const float* gate_b = (const float*)d_in[2];
  const float* patch_w = (const float*)d_in[3];
  const float* patch_b = (const float*)d_in[4];
  const float* cls    = (const float*)d_in[5];
  const float* pos    = (const float*)d_in[6];
  const float* ln1_w  = (const float*)d_in[7];
  const float* ln1_b  = (const float*)d_in[8];
  const float* qkv_w  = (const float*)d_in[9];
  const float* qkv_b  = (const float*)d_in[10];
  const float* proj_w = (const float*)d_in[11];
  const float* proj_b = (const float*)d_in[12];
  const float* ln2_w  = (const float*)d_in[13];
  const float* ln2_b  = (const float*)d_in[14];
  const float* fc1_w  = (const float*)d_in[15];
  const float* fc1_b  = (const float*)d_in[16];
  const float* fc2_w  = (const float*)d_in[17];
  const float* fc2_b  = (const float*)d_in[18];
  const float* norm_w = (const float*)d_in[19];
  const float* norm_b = (const float*)d_in[20];
  const float* head_w = (const float*)d_in[21];
  const float* head_b = (const float*)d_in[22];

  float* ws = (float*)d_ws;
  int* idx   = (int*)ws;                      // 64 floats reserved
  float* t   = ws + 64;                       // B*T*D
  float* h   = t + (size_t)B_ * T_ * D_;      // B*T*D
  float* qkv = h + (size_t)B_ * T_ * D_;      // B*T*3D
  float* o   = qkv + (size_t)B_ * T_ * 3 * D_;// B*T*D
  float* u   = o + (size_t)B_ * T_ * D_;      // B*T*FF

  gate_kernel<<<B_, 256, 0, stream>>>(x, gate_w, gate_b, idx);
  cls_kernel<<<B_, D_, 0, stream>>>(cls, pos, idx, t);
  patch_kernel<<<dim3(14, B_), D_, 0, stream>>>(x, patch_w, patch_b, pos, idx, t);
  for (int l = 0; l < L_; ++l) {
    ln_kernel<<<dim3(50, B_), 256, 0, stream>>>(t, h, ln1_w, ln1_b, idx, l);
    gemm_kernel<0><<<dim3(18, 4, B_), 256, 0, stream>>>(h, qkv_w, qkv_b, qkv, idx, l, D_, 3 * D_);
    attn_kernel<<<dim3(13, H_, B_), 256, 0, stream>>>(qkv, o);
    gemm_kernel<1><<<dim3(6, 4, B_), 256, 0, stream>>>(o, proj_w, proj_b, t, idx, l, D_, D_);
    ln_kernel<<<dim3(50, B_), 256, 0, stream>>>(t, h, ln2_w, ln2_b, idx, l);
    gemm_kernel<2><<<dim3(24, 4, B_), 256, 0, stream>>>(h, fc1_w, fc1_b, u, idx, l, D_, FF_);
    gemm_kernel<1><<<dim3(6, 4, B_), 256, 0, stream>>>(u, fc2_w, fc2_b, t, idx, l, FF_, D_);
  }
  head_kernel<<<B_, 64, 0, stream>>>(t, norm_w, norm_b, head_w, head_b, idx, (float*)d_out);
}